// Round 4
// baseline (269.182 us; speedup 1.0000x reference)
//
#include <hip/hip_runtime.h>
#include <math.h>

#define B    1024
#define NI   32
#define NH   1024

// ws layout (floats), degree-sorted hidden index "s":
//   W1t [32][1024] : W1t[j][s] = m1-masked W1[orig(s)][j]
//   b1s [1088]     : sorted b1 + 64 zero pad (phase-A lane overread)
//   b2s [1024]
//   W2t [1024][1024]: W2t[sh][sg] = m2-masked W2[og][oh]  (sh = h1 unit, sg = h2 unit)
//   W3s [64][1024] : m3-masked, sorted columns
#define OFF_W1T 0
#define OFF_B1S (32 * 1024)            // 32768
#define OFF_B2S (OFF_B1S + 1088)       // 33856
#define OFF_W2T (OFF_B2S + 1024)       // 34880
#define OFF_W3S (OFF_W2T + 1024*1024)  // 1083456
// total = 1148992 floats (~4.6 MB). Phase-B zero-weighted overreads (u >= cnt)
// of up to ~3 rows past W2T land inside W3S (finite, multiplied by 0.0).

// orig h -> (deg, sorted idx). deg0 has 34 units (h=31k), deg d>=1 has 33.
__device__ __forceinline__ int sidx(int h, int& d) {
    d = h % 31;
    int k = h / 31;
    return (d == 0) ? k : (33 * d + 1 + k);
}

// All-coalesced float4 reads; scattered 4B writes (fire-and-forget).
// blockIdx ranges: [0,1024) W2t, [1024,1088) W3s, [1088,1120) W1t, [1120,1124) biases
__global__ void prep_all(const float* __restrict__ W1, const float* __restrict__ b1,
                         const float* __restrict__ W2, const float* __restrict__ b2,
                         const float* __restrict__ W3, float* __restrict__ ws) {
    const int bid = blockIdx.x, t = threadIdx.x;
    if (bid < 1024) {                                   // W2t: 256K float4 reads
        int idx4 = bid * 256 + t;
        int og   = idx4 >> 8;                           // W2 row (h2 unit g)
        int oh0  = (idx4 & 255) * 4;                    // W2 col (h1 unit h)
        float4 v = *(const float4*)(W2 + (size_t)og * NH + oh0);
        int dg; int sg = sidx(og, dg);
        float vv[4] = {v.x, v.y, v.z, v.w};
#pragma unroll
        for (int c = 0; c < 4; ++c) {
            int dh; int sh = sidx(oh0 + c, dh);
            ws[OFF_W2T + (size_t)sh * NH + sg] = (dg >= dh) ? vv[c] : 0.0f;
        }
    } else if (bid < 1088) {                            // W3s: 16K float4 reads
        int idx4 = (bid - 1024) * 256 + t;
        int o  = idx4 >> 8;
        int h0 = (idx4 & 255) * 4;
        float4 v = *(const float4*)(W3 + (size_t)o * NH + h0);
        int od = (o & 31) - 1;
        float vv[4] = {v.x, v.y, v.z, v.w};
#pragma unroll
        for (int c = 0; c < 4; ++c) {
            int dh; int sh = sidx(h0 + c, dh);
            ws[OFF_W3S + o * NH + sh] = (od >= dh) ? vv[c] : 0.0f;
        }
    } else if (bid < 1120) {                            // W1t: 8K float4 reads
        int idx4 = (bid - 1088) * 256 + t;
        int h  = idx4 >> 3;
        int j0 = (idx4 & 7) * 4;
        float4 v = *(const float4*)(W1 + h * NI + j0);
        int dh; int sh = sidx(h, dh);
        float vv[4] = {v.x, v.y, v.z, v.w};
#pragma unroll
        for (int c = 0; c < 4; ++c)
            ws[OFF_W1T + (j0 + c) * NH + sh] = (dh >= (j0 + c)) ? vv[c] : 0.0f;
    } else {                                            // biases
        int h = (bid - 1120) * 256 + t;
        int dh; int sh = sidx(h, dh);
        ws[OFF_B1S + sh] = b1[h];
        ws[OFF_B2S + sh] = b2[h];
        if (h < 64) ws[OFF_B1S + NH + h] = 0.0f;        // pad
    }
}

// One block = 2 rows x 2 slice-waves. Wave sl=0 owns z2 chunks {0,3}, sl=1 owns
// {1,2} (mirrored pairing -> equal total work, <=1.25x per-step imbalance).
// x and a1 live in registers (readlane broadcast); LDS = 16-float partials only.
__global__ __launch_bounds__(256, 2) void made_scan(
        const float* __restrict__ inputs,
        const float* __restrict__ b3,
        const float* __restrict__ ws,
        float* __restrict__ out) {
    __shared__ float part[2][2][2][2];   // [buf][row][slice][{s0,s1}]

    const int tid  = threadIdx.x;
    const int lane = tid & 63;
    const int w    = tid >> 6;
    const int r    = w & 1;              // local row
    const int sl   = w >> 1;             // slice
    const int row  = blockIdx.x * 2 + r;
    const int q0   = sl;                 // chunk pair {sl, 3-sl}
    const int q1   = 3 - sl;

    const float* W1t = ws + OFF_W1T;
    const float* b1s = ws + OFF_B1S;
    const float* b2s = ws + OFF_B2S;
    const float* W2t = ws + OFF_W2T;
    const float* W3s = ws + OFF_W3S;

    float4 zA = ((const float4*)(b2s + 256 * q0))[lane];   // g = 256*q0 + 4*lane + c
    float4 zB = ((const float4*)(b2s + 256 * q1))[lane];
    float xin  = (lane < NI) ? inputs[row * NI + lane] : 0.0f;
    float b3v  = b3[lane];
    float xreg = 0.0f;                   // x_j lives in lane j
    float Jacc = 0.0f;

    for (int i = 0; i < NI; ++i) {
        const int goff = (i <= 1) ? 0 : (33 * (i - 1) + 1);
        const int cnt  = (i == 0) ? 0 : ((i == 1) ? 34 : 33);
        const int L    = (i == 0) ? 0 : (33 * i + 1);

        // ---- prefetch phase-C weights (static addresses; hide under A+B)
        const bool c0 = (256 * q0 < L), c1 = (256 * q1 < L);
        float4 wa0 = {0,0,0,0}, wb0 = {0,0,0,0}, wa1 = {0,0,0,0}, wb1 = {0,0,0,0};
        if (c0) {
            wa0 = ((const float4*)(W3s + (size_t)i * NH + 256 * q0))[lane];
            wb0 = ((const float4*)(W3s + (size_t)(NI + i) * NH + 256 * q0))[lane];
        }
        if (c1) {
            wa1 = ((const float4*)(W3s + (size_t)i * NH + 256 * q1))[lane];
            wb1 = ((const float4*)(W3s + (size_t)(NI + i) * NH + 256 * q1))[lane];
        }

        // ---- Phase A: a1 for units finalized this step (lane u = unit goff+u).
        // Fixed 32-tap: W1t masked zeros (j > i-1) and x_j = 0 (j >= i) make it exact.
        float a1 = 0.0f;
        if (i > 0) {
            const int su = goff + lane;
            float p0 = b1s[su], p1 = 0.0f, p2 = 0.0f, p3 = 0.0f;
#pragma unroll
            for (int j = 0; j < 32; j += 4) {
                p0 = fmaf(__shfl(xreg, j + 0, 64), W1t[(j + 0) * NH + su], p0);
                p1 = fmaf(__shfl(xreg, j + 1, 64), W1t[(j + 1) * NH + su], p1);
                p2 = fmaf(__shfl(xreg, j + 2, 64), W1t[(j + 2) * NH + su], p2);
                p3 = fmaf(__shfl(xreg, j + 3, 64), W1t[(j + 3) * NH + su], p3);
            }
            float z = (p0 + p1) + (p2 + p3);
            a1 = (lane < cnt) ? fmaxf(z, 0.0f) : 0.0f;
        }

        // ---- Phase B: z2 chunks += sum_u a1[u] * W2t[goff+u][chunk]
        if (i > 0) {
            const float* rb   = W2t + (size_t)goff * NH;
            const bool   act0 = (256 * (q0 + 1) > goff);   // q1 chunk: always active
#pragma unroll
            for (int u = 0; u < 36; u += 4) {
                float av0 = __shfl(a1, u + 0, 64), av1 = __shfl(a1, u + 1, 64);
                float av2 = __shfl(a1, u + 2, 64), av3 = __shfl(a1, u + 3, 64);
                if (act0) {
                    const float* cb = rb + 256 * q0;
                    float4 w0 = ((const float4*)(cb + (size_t)(u + 0) * NH))[lane];
                    float4 w1 = ((const float4*)(cb + (size_t)(u + 1) * NH))[lane];
                    float4 w2 = ((const float4*)(cb + (size_t)(u + 2) * NH))[lane];
                    float4 w3 = ((const float4*)(cb + (size_t)(u + 3) * NH))[lane];
                    zA.x = fmaf(av0, w0.x, zA.x); zA.y = fmaf(av0, w0.y, zA.y);
                    zA.z = fmaf(av0, w0.z, zA.z); zA.w = fmaf(av0, w0.w, zA.w);
                    zA.x = fmaf(av1, w1.x, zA.x); zA.y = fmaf(av1, w1.y, zA.y);
                    zA.z = fmaf(av1, w1.z, zA.z); zA.w = fmaf(av1, w1.w, zA.w);
                    zA.x = fmaf(av2, w2.x, zA.x); zA.y = fmaf(av2, w2.y, zA.y);
                    zA.z = fmaf(av2, w2.z, zA.z); zA.w = fmaf(av2, w2.w, zA.w);
                    zA.x = fmaf(av3, w3.x, zA.x); zA.y = fmaf(av3, w3.y, zA.y);
                    zA.z = fmaf(av3, w3.z, zA.z); zA.w = fmaf(av3, w3.w, zA.w);
                }
                {
                    const float* cb = rb + 256 * q1;
                    float4 w0 = ((const float4*)(cb + (size_t)(u + 0) * NH))[lane];
                    float4 w1 = ((const float4*)(cb + (size_t)(u + 1) * NH))[lane];
                    float4 w2 = ((const float4*)(cb + (size_t)(u + 2) * NH))[lane];
                    float4 w3 = ((const float4*)(cb + (size_t)(u + 3) * NH))[lane];
                    zB.x = fmaf(av0, w0.x, zB.x); zB.y = fmaf(av0, w0.y, zB.y);
                    zB.z = fmaf(av0, w0.z, zB.z); zB.w = fmaf(av0, w0.w, zB.w);
                    zB.x = fmaf(av1, w1.x, zB.x); zB.y = fmaf(av1, w1.y, zB.y);
                    zB.z = fmaf(av1, w1.z, zB.z); zB.w = fmaf(av1, w1.w, zB.w);
                    zB.x = fmaf(av2, w2.x, zB.x); zB.y = fmaf(av2, w2.y, zB.y);
                    zB.z = fmaf(av2, w2.z, zB.z); zB.w = fmaf(av2, w2.w, zB.w);
                    zB.x = fmaf(av3, w3.x, zB.x); zB.y = fmaf(av3, w3.y, zB.y);
                    zB.z = fmaf(av3, w3.z, zB.z); zB.w = fmaf(av3, w3.w, zB.w);
                }
            }
        }

        // ---- Phase C: slice partials of p[i], p[32+i] (W3s zeros beyond prefix L)
        float s0 = 0.0f, s1 = 0.0f;
        if (c0) {
            float hx = fmaxf(zA.x, 0.0f), hy = fmaxf(zA.y, 0.0f);
            float hz = fmaxf(zA.z, 0.0f), hw = fmaxf(zA.w, 0.0f);
            s0 = fmaf(wa0.x, hx, s0); s1 = fmaf(wb0.x, hx, s1);
            s0 = fmaf(wa0.y, hy, s0); s1 = fmaf(wb0.y, hy, s1);
            s0 = fmaf(wa0.z, hz, s0); s1 = fmaf(wb0.z, hz, s1);
            s0 = fmaf(wa0.w, hw, s0); s1 = fmaf(wb0.w, hw, s1);
        }
        if (c1) {
            float hx = fmaxf(zB.x, 0.0f), hy = fmaxf(zB.y, 0.0f);
            float hz = fmaxf(zB.z, 0.0f), hw = fmaxf(zB.w, 0.0f);
            s0 = fmaf(wa1.x, hx, s0); s1 = fmaf(wb1.x, hx, s1);
            s0 = fmaf(wa1.y, hy, s0); s1 = fmaf(wb1.y, hy, s1);
            s0 = fmaf(wa1.z, hz, s0); s1 = fmaf(wb1.z, hz, s1);
            s0 = fmaf(wa1.w, hw, s0); s1 = fmaf(wb1.w, hw, s1);
        }
#pragma unroll
        for (int m = 32; m >= 1; m >>= 1) {
            s0 += __shfl_xor(s0, m, 64);
            s1 += __shfl_xor(s1, m, 64);
        }
        if (lane == 0) { part[i & 1][r][sl][0] = s0; part[i & 1][r][sl][1] = s1; }
        __syncthreads();

        float p0 = part[i & 1][r][0][0] + part[i & 1][r][1][0] + __shfl(b3v, i, 64);
        float p1 = part[i & 1][r][0][1] + part[i & 1][r][1][1] + __shfl(b3v, NI + i, 64);
        float e2 = __expf(2.0f * fminf(p1, 15.0f));       // tanh via exp; exact sat both ends
        float a  = (e2 - 1.0f) / (e2 + 1.0f);
        float xi = fmaf(__shfl(xin, i, 64), __expf(a), p0);
        if (lane == i) xreg = xi;
        Jacc -= a;
    }

    if (sl == 0 && lane < NI) out[row * NI + lane] = xreg;
    if (sl == 0 && lane == 0) out[B * NI + row] = Jacc;
}

extern "C" void kernel_launch(void* const* d_in, const int* in_sizes, int n_in,
                              void* d_out, int out_size, void* d_ws, size_t ws_size,
                              hipStream_t stream) {
    const float* inputs = (const float*)d_in[0];
    const float* W1     = (const float*)d_in[1];
    const float* b1     = (const float*)d_in[2];
    const float* W2     = (const float*)d_in[3];
    const float* b2     = (const float*)d_in[4];
    const float* W3     = (const float*)d_in[5];
    const float* b3     = (const float*)d_in[6];
    float* out = (float*)d_out;
    float* ws  = (float*)d_ws;

    prep_all<<<1124, 256, 0, stream>>>(W1, b1, W2, b2, W3, ws);
    made_scan<<<B / 2, 256, 0, stream>>>(inputs, b3, ws, out);
}

// Round 5
// 228.861 us; speedup vs baseline: 1.1762x; 1.1762x over previous
//
#include <hip/hip_runtime.h>
#include <math.h>

#define B    1024
#define NI   32
#define NH   1024

// ws layout (floats), degree-sorted hidden index "s":
//   W1t [32][1024]  : W1t[j][s] = m1-masked W1[orig(s)][j]
//   b1s [1088]      : sorted b1 + 64 zero pad (phase-A lane overread)
//   b2s [1024]
//   W2t [1024][1024]: W2t[sh][sg] = m2-masked W2[orig(sg)][orig(sh)]
//   W3s [64][1024]  : m3-masked, sorted columns
#define OFF_W1T 0
#define OFF_B1S (NI * NH)              // 32768
#define OFF_B2S (OFF_B1S + NH + 64)    // 33856
#define OFF_W2T (OFF_B2S + NH)         // 34880
#define OFF_W3S (OFF_W2T + NH * NH)    // 1083456
// total = 1148992 floats (~4.6 MB). Phase-B zero-weighted u>=cnt overreads of
// up to ~3 rows past W2T land inside W3S (finite, multiplied by 0.0).

// sorted s -> (deg, orig h). deg0 has 34 units (h=31k), deg d>=1 has 33.
__device__ __forceinline__ void s2o(int s, int& d, int& o) {
    int k;
    if (s < 34) { d = 0; k = s; }
    else        { d = (s - 34) / 33 + 1; k = (s - 34) % 33; }
    o = d + 31 * k;
}

// Gather-READ / coalesced-WRITE prep: block = one output row; scattered reads
// pipeline freely (no write-allocate storm from scattered stores).
// blockIdx: [0,1024) W2t rows, [1024,1088) W3s rows, [1088,1120) W1t rows, 1120 biases
__global__ void prep_all(const float* __restrict__ W1, const float* __restrict__ b1,
                         const float* __restrict__ W2, const float* __restrict__ b2,
                         const float* __restrict__ W3, float* __restrict__ ws) {
    const int bid = blockIdx.x, t = threadIdx.x;
    if (bid < NH) {                                     // W2t row sh
        const int sh = bid; int dh, oh; s2o(sh, dh, oh);
        float vv[4];
#pragma unroll
        for (int c = 0; c < 4; ++c) {
            int sg = 4 * t + c; int dg, og; s2o(sg, dg, og);
            vv[c] = (dg >= dh) ? W2[(size_t)og * NH + oh] : 0.0f;
        }
        ((float4*)(ws + OFF_W2T + (size_t)sh * NH))[t] =
            make_float4(vv[0], vv[1], vv[2], vv[3]);
    } else if (bid < NH + 64) {                         // W3s row o
        const int o = bid - NH, od = (o & 31) - 1;
        float vv[4];
#pragma unroll
        for (int c = 0; c < 4; ++c) {
            int s = 4 * t + c; int dg, og; s2o(s, dg, og);
            vv[c] = (od >= dg) ? W3[(size_t)o * NH + og] : 0.0f;
        }
        ((float4*)(ws + OFF_W3S + (size_t)o * NH))[t] =
            make_float4(vv[0], vv[1], vv[2], vv[3]);
    } else if (bid < NH + 64 + NI) {                    // W1t row j
        const int j = bid - NH - 64;
        float vv[4];
#pragma unroll
        for (int c = 0; c < 4; ++c) {
            int s = 4 * t + c; int dg, og; s2o(s, dg, og);
            vv[c] = (dg >= j) ? W1[og * NI + j] : 0.0f;
        }
        ((float4*)(ws + OFF_W1T + (size_t)j * NH))[t] =
            make_float4(vv[0], vv[1], vv[2], vv[3]);
    } else {                                            // biases + pad
        float v1[4], v2[4];
#pragma unroll
        for (int c = 0; c < 4; ++c) {
            int s = 4 * t + c; int dg, og; s2o(s, dg, og);
            v1[c] = b1[og]; v2[c] = b2[og];
        }
        ((float4*)(ws + OFF_B1S))[t] = make_float4(v1[0], v1[1], v1[2], v1[3]);
        ((float4*)(ws + OFF_B2S))[t] = make_float4(v2[0], v2[1], v2[2], v2[3]);
        if (t < 16) ((float4*)(ws + OFF_B1S + NH))[t] = make_float4(0, 0, 0, 0);
    }
}

// Block = 4 batch rows x 4 slice-waves. Wave sl owns z2[256sl, 256sl+256) for
// all 4 rows (4 float4 accumulators) -> each W2t load feeds 16 FMAs (4x row
// reuse cuts L2 traffic to ~0.67 GB). One barrier/step (partials exchange).
__global__ __launch_bounds__(256, 2) void made_scan(
        const float* __restrict__ inputs,
        const float* __restrict__ b3,
        const float* __restrict__ ws,
        float* __restrict__ out) {
    __shared__ float part[2][4][8];      // [buf][sl][2r+{s0,s1}]

    const int lane = threadIdx.x & 63;
    const int sl   = threadIdx.x >> 6;
    const int row0 = blockIdx.x * 4;
    const int gb   = sl * 256;

    const float* W1t = ws + OFF_W1T;
    const float* b1s = ws + OFF_B1S;
    const float* b2s = ws + OFF_B2S;
    const float* W2t = ws + OFF_W2T;
    const float* W3s = ws + OFF_W3S;

    float4 acc0, acc1, acc2, acc3;       // z2 slice per row; g = gb + 4*lane + c
    acc0 = acc1 = acc2 = acc3 = ((const float4*)(b2s + gb))[lane];

    float xin0 = (lane < NI) ? inputs[(row0 + 0) * NI + lane] : 0.0f;
    float xin1 = (lane < NI) ? inputs[(row0 + 1) * NI + lane] : 0.0f;
    float xin2 = (lane < NI) ? inputs[(row0 + 2) * NI + lane] : 0.0f;
    float xin3 = (lane < NI) ? inputs[(row0 + 3) * NI + lane] : 0.0f;
    float b3v = b3[lane];
    float xr0 = 0, xr1 = 0, xr2 = 0, xr3 = 0;   // x_j lives in lane j, per row
    float J0 = 0, J1 = 0, J2 = 0, J3 = 0;

    for (int i = 0; i < NI; ++i) {
        const int goff = (i <= 1) ? 0 : (33 * (i - 1) + 1);
        const int cnt  = (i == 0) ? 0 : ((i == 1) ? 34 : 33);
        const int L    = (i == 0) ? 0 : (33 * i + 1);
        const bool doB = (i > 0) && (gb + 256 > goff);
        const bool doC = (gb < L);

        // prefetch phase-C weights (shared across rows)
        float4 wa = make_float4(0, 0, 0, 0), wb = make_float4(0, 0, 0, 0);
        if (doC) {
            wa = ((const float4*)(W3s + (size_t)i * NH + gb))[lane];
            wb = ((const float4*)(W3s + (size_t)(NI + i) * NH + gb))[lane];
        }

        if (doB) {
            // ---- Phase A: a1 for the cnt units finalized this step, 4 rows.
            // W1t loads shared across rows. Taps beyond i are exact zeros
            // (masked W1t / xr=0), so round i up to a multiple of 4.
            const int su = goff + lane;
            float bz = b1s[su];
            float z0 = bz, z1 = bz, z2 = bz, z3 = bz;
            const int jmax = (i + 3) & ~3;
            for (int j = 0; j < jmax; j += 4) {
#pragma unroll
                for (int jj = 0; jj < 4; ++jj) {
                    float w1v = W1t[(j + jj) * NH + su];
                    z0 = fmaf(__shfl(xr0, j + jj, 64), w1v, z0);
                    z1 = fmaf(__shfl(xr1, j + jj, 64), w1v, z1);
                    z2 = fmaf(__shfl(xr2, j + jj, 64), w1v, z2);
                    z3 = fmaf(__shfl(xr3, j + jj, 64), w1v, z3);
                }
            }
            const bool ok = lane < cnt;
            float a10 = ok ? fmaxf(z0, 0.0f) : 0.0f;
            float a11 = ok ? fmaxf(z1, 0.0f) : 0.0f;
            float a12 = ok ? fmaxf(z2, 0.0f) : 0.0f;
            float a13 = ok ? fmaxf(z3, 0.0f) : 0.0f;

            // ---- Phase B: 1 float4 load -> 16 FMAs (4 rows)
            const float* rb = W2t + (size_t)goff * NH + gb;
#pragma unroll
            for (int u = 0; u < 36; u += 2) {
                float4 w0 = ((const float4*)(rb + (size_t)u * NH))[lane];
                float4 w1 = ((const float4*)(rb + (size_t)(u + 1) * NH))[lane];
                float c00 = __shfl(a10, u, 64),     c01 = __shfl(a11, u, 64);
                float c02 = __shfl(a12, u, 64),     c03 = __shfl(a13, u, 64);
                float c10 = __shfl(a10, u + 1, 64), c11 = __shfl(a11, u + 1, 64);
                float c12 = __shfl(a12, u + 1, 64), c13 = __shfl(a13, u + 1, 64);
                acc0.x = fmaf(c00, w0.x, acc0.x); acc0.y = fmaf(c00, w0.y, acc0.y);
                acc0.z = fmaf(c00, w0.z, acc0.z); acc0.w = fmaf(c00, w0.w, acc0.w);
                acc1.x = fmaf(c01, w0.x, acc1.x); acc1.y = fmaf(c01, w0.y, acc1.y);
                acc1.z = fmaf(c01, w0.z, acc1.z); acc1.w = fmaf(c01, w0.w, acc1.w);
                acc2.x = fmaf(c02, w0.x, acc2.x); acc2.y = fmaf(c02, w0.y, acc2.y);
                acc2.z = fmaf(c02, w0.z, acc2.z); acc2.w = fmaf(c02, w0.w, acc2.w);
                acc3.x = fmaf(c03, w0.x, acc3.x); acc3.y = fmaf(c03, w0.y, acc3.y);
                acc3.z = fmaf(c03, w0.z, acc3.z); acc3.w = fmaf(c03, w0.w, acc3.w);
                acc0.x = fmaf(c10, w1.x, acc0.x); acc0.y = fmaf(c10, w1.y, acc0.y);
                acc0.z = fmaf(c10, w1.z, acc0.z); acc0.w = fmaf(c10, w1.w, acc0.w);
                acc1.x = fmaf(c11, w1.x, acc1.x); acc1.y = fmaf(c11, w1.y, acc1.y);
                acc1.z = fmaf(c11, w1.z, acc1.z); acc1.w = fmaf(c11, w1.w, acc1.w);
                acc2.x = fmaf(c12, w1.x, acc2.x); acc2.y = fmaf(c12, w1.y, acc2.y);
                acc2.z = fmaf(c12, w1.z, acc2.z); acc2.w = fmaf(c12, w1.w, acc2.w);
                acc3.x = fmaf(c13, w1.x, acc3.x); acc3.y = fmaf(c13, w1.y, acc3.y);
                acc3.z = fmaf(c13, w1.z, acc3.z); acc3.w = fmaf(c13, w1.w, acc3.w);
            }
        }

        // ---- Phase C: slice partials (W3s zeros beyond prefix L)
        float s00 = 0, s01 = 0, s10 = 0, s11 = 0;
        float s20 = 0, s21 = 0, s30 = 0, s31 = 0;
        if (doC) {
            float hx, hy, hz, hw;
            hx = fmaxf(acc0.x, 0.0f); hy = fmaxf(acc0.y, 0.0f);
            hz = fmaxf(acc0.z, 0.0f); hw = fmaxf(acc0.w, 0.0f);
            s00 = fmaf(wa.x, hx, fmaf(wa.y, hy, fmaf(wa.z, hz, wa.w * hw)));
            s01 = fmaf(wb.x, hx, fmaf(wb.y, hy, fmaf(wb.z, hz, wb.w * hw)));
            hx = fmaxf(acc1.x, 0.0f); hy = fmaxf(acc1.y, 0.0f);
            hz = fmaxf(acc1.z, 0.0f); hw = fmaxf(acc1.w, 0.0f);
            s10 = fmaf(wa.x, hx, fmaf(wa.y, hy, fmaf(wa.z, hz, wa.w * hw)));
            s11 = fmaf(wb.x, hx, fmaf(wb.y, hy, fmaf(wb.z, hz, wb.w * hw)));
            hx = fmaxf(acc2.x, 0.0f); hy = fmaxf(acc2.y, 0.0f);
            hz = fmaxf(acc2.z, 0.0f); hw = fmaxf(acc2.w, 0.0f);
            s20 = fmaf(wa.x, hx, fmaf(wa.y, hy, fmaf(wa.z, hz, wa.w * hw)));
            s21 = fmaf(wb.x, hx, fmaf(wb.y, hy, fmaf(wb.z, hz, wb.w * hw)));
            hx = fmaxf(acc3.x, 0.0f); hy = fmaxf(acc3.y, 0.0f);
            hz = fmaxf(acc3.z, 0.0f); hw = fmaxf(acc3.w, 0.0f);
            s30 = fmaf(wa.x, hx, fmaf(wa.y, hy, fmaf(wa.z, hz, wa.w * hw)));
            s31 = fmaf(wb.x, hx, fmaf(wb.y, hy, fmaf(wb.z, hz, wb.w * hw)));
        }
#pragma unroll
        for (int m = 32; m >= 1; m >>= 1) {
            s00 += __shfl_xor(s00, m, 64); s01 += __shfl_xor(s01, m, 64);
            s10 += __shfl_xor(s10, m, 64); s11 += __shfl_xor(s11, m, 64);
            s20 += __shfl_xor(s20, m, 64); s21 += __shfl_xor(s21, m, 64);
            s30 += __shfl_xor(s30, m, 64); s31 += __shfl_xor(s31, m, 64);
        }
        if (lane == 0) {
            float* pp = &part[i & 1][sl][0];
            ((float4*)pp)[0] = make_float4(s00, s01, s10, s11);
            ((float4*)pp)[1] = make_float4(s20, s21, s30, s31);
        }
        __syncthreads();

        // combine slices; rows packed into lanes (lane&3) -> one tanh/exp
        const float* pb = &part[i & 1][0][0];
        float4 Aq = ((const float4*)pb)[0], Bq = ((const float4*)pb)[1];
        float4 t2, t3;
        t2 = ((const float4*)pb)[2]; t3 = ((const float4*)pb)[3];
        Aq.x += t2.x; Aq.y += t2.y; Aq.z += t2.z; Aq.w += t2.w;
        Bq.x += t3.x; Bq.y += t3.y; Bq.z += t3.z; Bq.w += t3.w;
        t2 = ((const float4*)pb)[4]; t3 = ((const float4*)pb)[5];
        Aq.x += t2.x; Aq.y += t2.y; Aq.z += t2.z; Aq.w += t2.w;
        Bq.x += t3.x; Bq.y += t3.y; Bq.z += t3.z; Bq.w += t3.w;
        t2 = ((const float4*)pb)[6]; t3 = ((const float4*)pb)[7];
        Aq.x += t2.x; Aq.y += t2.y; Aq.z += t2.z; Aq.w += t2.w;
        Bq.x += t3.x; Bq.y += t3.y; Bq.z += t3.z; Bq.w += t3.w;
        // Aq = (p00,p01,p10,p11), Bq = (p20,p21,p30,p31)
        const int lr = lane & 3;
        float p0p = (lr == 0) ? Aq.x : (lr == 1) ? Aq.z : (lr == 2) ? Bq.x : Bq.z;
        float p1p = (lr == 0) ? Aq.y : (lr == 1) ? Aq.w : (lr == 2) ? Bq.y : Bq.w;
        p0p += __shfl(b3v, i, 64);
        p1p += __shfl(b3v, NI + i, 64);
        float xi0 = __shfl(xin0, i, 64), xi1 = __shfl(xin1, i, 64);
        float xi2 = __shfl(xin2, i, 64), xi3 = __shfl(xin3, i, 64);
        float xinp = (lr == 0) ? xi0 : (lr == 1) ? xi1 : (lr == 2) ? xi2 : xi3;
        float e2 = __expf(2.0f * fminf(p1p, 15.0f));   // tanh; exact sat both ends
        float ap = (e2 - 1.0f) / (e2 + 1.0f);
        float xp = fmaf(xinp, __expf(ap), p0p);
        float av0 = __shfl(ap, 0, 64), av1 = __shfl(ap, 1, 64);
        float av2 = __shfl(ap, 2, 64), av3 = __shfl(ap, 3, 64);
        float xv0 = __shfl(xp, 0, 64), xv1 = __shfl(xp, 1, 64);
        float xv2 = __shfl(xp, 2, 64), xv3 = __shfl(xp, 3, 64);
        J0 -= av0; J1 -= av1; J2 -= av2; J3 -= av3;
        if (lane == i) { xr0 = xv0; xr1 = xv1; xr2 = xv2; xr3 = xv3; }
    }

    if (sl == 0) {
        if (lane < NI) {
            out[(row0 + 0) * NI + lane] = xr0;
            out[(row0 + 1) * NI + lane] = xr1;
            out[(row0 + 2) * NI + lane] = xr2;
            out[(row0 + 3) * NI + lane] = xr3;
        }
        if (lane < 4) {
            float Jv = (lane == 0) ? J0 : (lane == 1) ? J1 : (lane == 2) ? J2 : J3;
            out[B * NI + row0 + lane] = Jv;
        }
    }
}

extern "C" void kernel_launch(void* const* d_in, const int* in_sizes, int n_in,
                              void* d_out, int out_size, void* d_ws, size_t ws_size,
                              hipStream_t stream) {
    const float* inputs = (const float*)d_in[0];
    const float* W1     = (const float*)d_in[1];
    const float* b1     = (const float*)d_in[2];
    const float* W2     = (const float*)d_in[3];
    const float* b2     = (const float*)d_in[4];
    const float* W3     = (const float*)d_in[5];
    const float* b3     = (const float*)d_in[6];
    float* out = (float*)d_out;
    float* ws  = (float*)d_ws;

    prep_all<<<NH + 64 + NI + 1, 256, 0, stream>>>(W1, b1, W2, b2, W3, ws);
    made_scan<<<B / 4, 256, 0, stream>>>(inputs, b3, ws, out);
}